// Round 5
// baseline (249.525 us; speedup 1.0000x reference)
//
#include <hip/hip_runtime.h>
#include <hip/hip_bf16.h>

typedef __attribute__((ext_vector_type(4))) float f32x4;
typedef __attribute__((ext_vector_type(8))) short bf16x8;
typedef unsigned int u32;
typedef unsigned short u16;

#define DEV static __device__ __forceinline__

// T=32,B=32 -> TB=1024 ; N=64 ; D=1024 ; H=16 ; HD=64
// d_out: attended [1024x1024] f32 @0 ; mean_attn [1024x64] @1048576 ; logits [1024x16x64] @1114112

DEV u16 f2bf(float x){                       // RNE f32->bf16
  union { float f; u32 u; } v; v.f = x;
  u32 r = v.u + 0x7FFFu + ((v.u >> 16) & 1u);
  return (u16)(r >> 16);
}
DEV float bf2f(u16 s){
  union { u32 u; float f; } v; v.u = ((u32)s) << 16;
  return v.f;
}

#define MFMA16(a,b,c) __builtin_amdgcn_mfma_f32_16x16x32_bf16((a),(b),(c),0,0,0)

// f32 token-buffer swizzle for 4-token rounds: XOR byte bits 4-6 by a token hash.
// Rows 0..3 -> 0x00,0x30,0x40,0x70: QK^T fragment reads land <=2-way (free, m136).
// Involution; 16B-granular so global_load_lds source stays 16B-aligned & coalesced.
#define SWZ(n) ((((n)&3)<<5) | (((n)&1)<<4))

// lgkm-only block barrier: orders LDS, does NOT drain vmcnt (keeps global_load_lds
// staging in flight across it).
DEV void bar_lgkm(){
  __builtin_amdgcn_sched_barrier(0);
  asm volatile("s_waitcnt lgkmcnt(0)" ::: "memory");
  __builtin_amdgcn_s_barrier();
  __builtin_amdgcn_sched_barrier(0);
}
// full barrier: drains staging (vmcnt) + LDS, then barrier.
DEV void bar_full(){
  __builtin_amdgcn_sched_barrier(0);
  asm volatile("s_waitcnt vmcnt(0) lgkmcnt(0)" ::: "memory");
  __builtin_amdgcn_s_barrier();
  __builtin_amdgcn_sched_barrier(0);
}

// 8x f32 -> bf16x8 via packed RNE converts
DEV bf16x8 cvt8(f32x4 lo, f32x4 hi){
  union { u32 u[4]; bf16x8 v; } r;
  asm("v_cvt_pk_bf16_f32 %0, %1, %2" : "=v"(r.u[0]) : "v"(lo.x), "v"(lo.y));
  asm("v_cvt_pk_bf16_f32 %0, %1, %2" : "=v"(r.u[1]) : "v"(lo.z), "v"(lo.w));
  asm("v_cvt_pk_bf16_f32 %0, %1, %2" : "=v"(r.u[2]) : "v"(hi.x), "v"(hi.y));
  asm("v_cvt_pk_bf16_f32 %0, %1, %2" : "=v"(r.u[3]) : "v"(hi.z), "v"(hi.w));
  return r.v;
}

// Stage 4 tokens (f32, 16KB) of (tbn, tk0..tk0+3) into buffer bb via async
// global_load_lds; wave w stages token tk0+w. LDS dest is linear (HW: wave-uniform
// base + lane*16); the bank swizzle is applied by pre-swizzling the per-lane GLOBAL
// source address: LDS[y] = G[y ^ SWZ(w)], reader uses LDS[x ^ SWZ(tok)] = G[x].
DEV void stage4(const float* __restrict__ tokens, int tbn, int tk0,
                char* smem, int bb, int w, int l){
  char* ldsb = smem + (size_t)bb*16384 + (size_t)w*4096;
  const char* gb = (const char*)tokens + (size_t)tbn*262144 + (size_t)(tk0 + w)*4096;
  #pragma unroll
  for (int j = 0; j < 4; ++j){
    const int inner = ((j*1024) + l*16) ^ SWZ(w);
    __builtin_amdgcn_global_load_lds(
        (const __attribute__((address_space(1))) u32*)(gb + inner),
        (__attribute__((address_space(3))) u32*)(ldsb + j*1024),
        16, 0, 0);
  }
}

// ============================ 5-kernel pipeline (the timed path) ============================
__global__ __launch_bounds__(256) void k_convert(
    const float* __restrict__ Wq, const float* __restrict__ Wk, const float* __restrict__ Wv,
    u16* __restrict__ WqT, u16* __restrict__ WkB, u16* __restrict__ WvT){
  __shared__ u16 tile[64][65];
  const int which = blockIdx.y;
  const float* src = which==0 ? Wq : (which==1 ? Wk : Wv);
  const int bi = (blockIdx.x >> 4) << 6;
  const int bj = (blockIdx.x & 15) << 6;
  const int t  = threadIdx.x;
  #pragma unroll
  for (int k2 = 0; k2 < 16; ++k2){
    int e = t + (k2 << 8);
    int r = e >> 6, c = e & 63;
    tile[r][c] = f2bf(src[(size_t)(bi + r)*1024 + bj + c]);
  }
  __syncthreads();
  if (which == 1){
    #pragma unroll
    for (int k2 = 0; k2 < 16; ++k2){
      int e = t + (k2 << 8); int r = e >> 6, c = e & 63;
      WkB[(size_t)(bi + r)*1024 + bj + c] = tile[r][c];
    }
  } else {
    u16* dst = which==0 ? WqT : WvT;
    #pragma unroll
    for (int k2 = 0; k2 < 16; ++k2){
      int e = t + (k2 << 8); int r = e >> 6, c = e & 63;
      dst[(size_t)(bj + r)*1024 + bi + c] = tile[c][r];
    }
  }
}

__global__ __launch_bounds__(256) void k_qproj(
    const float* __restrict__ qv, const u16* __restrict__ WqT, const float* __restrict__ bq,
    float* __restrict__ qf, u16* __restrict__ qb){
  const int l = threadIdx.x & 63, w = threadIdx.x >> 6;
  const int wm = w & 1, wn = w >> 1;
  const int g = l >> 4, li = l & 15;
  const int m_base = blockIdx.x*64 + wm*32;
  const int n_base = blockIdx.y*64 + wn*32;
  f32x4 acc[2][2];
  #pragma unroll
  for (int i=0;i<2;++i)
    #pragma unroll
    for (int j=0;j<2;++j) acc[i][j] = (f32x4)0.0f;

  #pragma unroll 4
  for (int kb = 0; kb < 32; ++kb){
    const int k0 = kb*32 + g*8;
    bf16x8 a[2], b[2];
    #pragma unroll
    for (int rt = 0; rt < 2; ++rt){
      const float* p = qv + (size_t)(m_base + rt*16 + li)*1024 + k0;
      f32x4 lo = *(const f32x4*)p;
      f32x4 hi = *(const f32x4*)(p+4);
      union { u16 s[8]; bf16x8 v; } u;
      u.s[0]=f2bf(lo.x); u.s[1]=f2bf(lo.y); u.s[2]=f2bf(lo.z); u.s[3]=f2bf(lo.w);
      u.s[4]=f2bf(hi.x); u.s[5]=f2bf(hi.y); u.s[6]=f2bf(hi.z); u.s[7]=f2bf(hi.w);
      a[rt] = u.v;
    }
    #pragma unroll
    for (int ct = 0; ct < 2; ++ct)
      b[ct] = *(const bf16x8*)(WqT + (size_t)(n_base + ct*16 + li)*1024 + k0);
    #pragma unroll
    for (int rt = 0; rt < 2; ++rt)
      #pragma unroll
      for (int ct = 0; ct < 2; ++ct)
        acc[rt][ct] = MFMA16(a[rt], b[ct], acc[rt][ct]);
  }
  #pragma unroll
  for (int rt=0;rt<2;++rt)
    #pragma unroll
    for (int ct=0;ct<2;++ct)
      #pragma unroll
      for (int r=0;r<4;++r){
        int m = m_base + rt*16 + g*4 + r;   // C/D map: row=(lane>>4)*4+reg, col=lane&15
        int n = n_base + ct*16 + li;
        float val = acc[rt][ct][r] + bq[n];
        qf[(size_t)m*1024 + n] = val;
        qb[(size_t)m*1024 + n] = f2bf(val);
      }
}

__global__ __launch_bounds__(256) void k_umat(
    const u16* __restrict__ qb, const u16* __restrict__ WkB, u16* __restrict__ U){
  __shared__ __align__(16) u16 stile[64][64];
  const int l = threadIdx.x & 63, w = threadIdx.x >> 6;
  const int wm = w & 1, wn = w >> 1, g = l >> 4, li = l & 15;
  const int tb0 = blockIdx.x*64, d0 = blockIdx.y*64, h = blockIdx.z;
  f32x4 acc[2][2];
  #pragma unroll
  for (int i=0;i<2;++i)
    #pragma unroll
    for (int j=0;j<2;++j) acc[i][j] = (f32x4)0.0f;

  #pragma unroll
  for (int kb = 0; kb < 2; ++kb){
    const int k0 = h*64 + kb*32 + g*8;
    bf16x8 a[2], b[2];
    #pragma unroll
    for (int rt=0;rt<2;++rt)
      a[rt] = *(const bf16x8*)(qb + (size_t)(tb0 + wm*32 + rt*16 + li)*1024 + k0);
    #pragma unroll
    for (int ct=0;ct<2;++ct)
      b[ct] = *(const bf16x8*)(WkB + (size_t)(d0 + wn*32 + ct*16 + li)*1024 + k0);
    #pragma unroll
    for (int rt=0;rt<2;++rt)
      #pragma unroll
      for (int ct=0;ct<2;++ct)
        acc[rt][ct] = MFMA16(a[rt], b[ct], acc[rt][ct]);
  }
  #pragma unroll
  for (int rt=0;rt<2;++rt)
    #pragma unroll
    for (int ct=0;ct<2;++ct)
      #pragma unroll
      for (int r=0;r<4;++r)
        stile[wm*32 + rt*16 + g*4 + r][wn*32 + ct*16 + li] = f2bf(acc[rt][ct][r]);
  __syncthreads();
  const int r = threadIdx.x >> 2, cg4 = threadIdx.x & 3;
  f32x4* dst = (f32x4*)(U + ((size_t)(tb0 + r)*16 + h)*1024 + d0 + cg4*16);
  const f32x4* s4 = (const f32x4*)(&stile[r][cg4*16]);
  dst[0] = s4[0]; dst[1] = s4[1];
}

// ---- k_attn: async global_load_lds double-buffered token stream (f32 in LDS) ----
// 16 rounds x 4 tokens per block (1 tb), 2x16KB buffers -> 41.7KB LDS -> 3 blocks/CU
// (vs 2 at the old 64KB): a third independent stream covers bar_full drain stalls.
// Stage for round r+1 issued right after round r's top bar_full (the only point
// buf[(r+1)&1] is provably free); drained by the NEXT top bar_full -> in-flight
// window = one full round. In-round barriers are lgkm-only.
#define K3_LDS 32768
__global__ __launch_bounds__(256, 3) void k_attn(
    const float* __restrict__ tokens, const float* __restrict__ gate,
    const u16* __restrict__ U, const float* __restrict__ qf, const float* __restrict__ bk,
    float* __restrict__ out_logits, float* __restrict__ out_mean, u16* __restrict__ ctx){
  extern __shared__ __align__(16) char smem[];
  __shared__ __align__(16) char sstat[8960];
  float* part_s   = (float*)(sstat);          // [4][64][4] 4096B
  float* logits_s = (float*)(sstat + 4096);   // [16][64]   4096B
  float* p_s      = (float*)(sstat + 8192);   // [4][16]    256B
  float* csum     = (float*)(sstat + 8448);   // [16]
  float* r_s      = (float*)(sstat + 8512);   // [16]
  float* mzs      = (float*)(sstat + 8576);   // [16][2]
  const int tb = blockIdx.x;
  const int tid = threadIdx.x;
  const int l = tid & 63, w = tid >> 6, g = l >> 4, li = l & 15;
  const int sh = tid >> 4, sj = tid & 15;

  // per-tb A-fragments: U[tb][h=li][D-slice of wave w]
  bf16x8 a[8];
  const bf16x8* Ub = (const bf16x8*)(U + (size_t)tb*16384);
  #pragma unroll
  for (int i = 0; i < 8; ++i)
    a[i] = Ub[li*128 + (w*8 + i)*4 + g];

  // csum[h] = q[tb, h*64:] . bk[h*64:]
  {
    const float* qp = qf + (size_t)tb*1024 + sh*64 + sj*4;
    const float* bp = bk + sh*64 + sj*4;
    float part = qp[0]*bp[0] + qp[1]*bp[1] + qp[2]*bp[2] + qp[3]*bp[3];
    part += __shfl_xor(part, 1); part += __shfl_xor(part, 2);
    part += __shfl_xor(part, 4); part += __shfl_xor(part, 8);
    if (sj == 0) csum[sh] = part;
  }

  float m_run = -1e30f, z_run = 0.0f;
  f32x4 cacc[4][4];
  #pragma unroll
  for (int i=0;i<4;++i)
    #pragma unroll
    for (int j=0;j<4;++j) cacc[i][j] = (f32x4)0.0f;

  stage4(tokens, tb, 0, smem, 0, w, l);       // prologue: chunk 0 -> buf0

  for (int r = 0; r < 16; ++r){
    const int n0 = r*4;
    char* bufc = smem + (size_t)(r & 1)*16384;

    bar_full();                               // (A) stage for r landed; buf[(r+1)&1] free
    if (r + 1 < 16)
      stage4(tokens, tb, (r+1)*4, smem, (r+1) & 1, w, l);

    // ---- QK^T: 4 tokens, K split 4 ways across waves; f32->bf16 at read ----
    {
      const int row = li & 3;                 // cols 4..15 duplicate rows (discarded)
      const int sw  = SWZ(row);
      f32x4 acc = (f32x4)0.0f;
      #pragma unroll
      for (int i = 0; i < 8; ++i){
        const int p0b = (w*8 + i)*128 + g*32;
        f32x4 lo = *(const f32x4*)(bufc + row*4096 + ((p0b     ) ^ sw));
        f32x4 hi = *(const f32x4*)(bufc + row*4096 + ((p0b + 16) ^ sw));
        acc = MFMA16(a[i], cvt8(lo, hi), acc);
      }
      *(f32x4*)(part_s + (size_t)(w*64 + l)*4) = acc;
    }
    bar_lgkm();                               // (B)

    // ---- online softmax over the 4-token chunk; reads 4 wave-partials ----
    if (sj < 4){
      const int idx = ((sh >> 2)*16 + sj)*4 + (sh & 3);
      float lv = part_s[idx] + part_s[256 + idx] + part_s[512 + idx] + part_s[768 + idx];
      lv = (lv + csum[sh])*0.125f + gate[(size_t)tb*64 + n0 + sj];
      logits_s[sh*64 + n0 + sj] = lv;
      out_logits[(size_t)tb*1024 + sh*64 + n0 + sj] = lv;
      float cm = lv;
      cm = fmaxf(cm, __shfl_xor(cm, 1));
      cm = fmaxf(cm, __shfl_xor(cm, 2));
      float m_new = fmaxf(m_run, cm);
      float rsc = __expf(m_run - m_new);
      float p0 = __expf(lv - m_new);
      float zs = p0;
      zs += __shfl_xor(zs, 1); zs += __shfl_xor(zs, 2);
      z_run = z_run * rsc + zs;
      m_run = m_new;
      p_s[sj*16 + sh] = p0;
      if (sj == 0){
        r_s[sh] = rsc;
        if (r == 15){ mzs[sh*2] = m_new; mzs[sh*2 + 1] = 1.0f / z_run; }
      }
    }
    bar_lgkm();                               // (D)

    // ---- PV: f32 tokens direct from LDS (no unpack), contiguous reads ----
    {
      float rr4[4];
      #pragma unroll
      for (int hh = 0; hh < 4; ++hh) rr4[hh] = r_s[w*4 + hh];
      #pragma unroll
      for (int dq = 0; dq < 4; ++dq)
        #pragma unroll
        for (int hh = 0; hh < 4; ++hh) cacc[dq][hh] *= rr4[hh];
      #pragma unroll
      for (int nl = 0; nl < 4; ++nl){
        const f32x4 p = *(const f32x4*)(p_s + nl*16 + w*4);
        const int swn = SWZ(nl);
        #pragma unroll
        for (int dq = 0; dq < 4; ++dq){
          const f32x4 t = *(const f32x4*)(bufc + (size_t)nl*4096 + ((dq*1024 + l*16) ^ swn));
          #pragma unroll
          for (int hh = 0; hh < 4; ++hh)
            cacc[dq][hh] += t * p[hh];
        }
      }
    }
  }

  // ---- epilogue (mzs/logits_s visible since barrier (D) of round 15) ----
  if (tid < 64){
    float s = 0.0f;
    #pragma unroll
    for (int h = 0; h < 16; ++h)
      s += __expf(logits_s[h*64 + tid] - mzs[h*2]) * mzs[h*2 + 1];
    out_mean[(size_t)tb*64 + tid] = s * 0.0625f;
  }
  #pragma unroll
  for (int hh = 0; hh < 4; ++hh){
    const int h = w*4 + hh;
    const float zinv = mzs[h*2 + 1];
    #pragma unroll
    for (int dq = 0; dq < 4; ++dq){
      f32x4 v = cacc[dq][hh];
      uint2 pk;
      pk.x = (u32)f2bf(v.x * zinv) | ((u32)f2bf(v.y * zinv) << 16);
      pk.y = (u32)f2bf(v.z * zinv) | ((u32)f2bf(v.w * zinv) << 16);
      *(uint2*)(ctx + ((size_t)tb*16 + h)*1024 + dq*256 + l*4) = pk;
    }
  }
}

__global__ __launch_bounds__(256) void k_attended(
    const u16* __restrict__ ctx, const u16* __restrict__ WvT, const float* __restrict__ bv,
    float* __restrict__ out_att){
  const int l = threadIdx.x & 63, w = threadIdx.x >> 6;
  const int wm = w & 1, wn = w >> 1, g = l >> 4, li = l & 15;
  const int tb0 = blockIdx.x*64, h = blockIdx.y;
  f32x4 acc[2][2];
  #pragma unroll
  for (int i=0;i<2;++i)
    #pragma unroll
    for (int j=0;j<2;++j) acc[i][j] = (f32x4)0.0f;

  #pragma unroll 4
  for (int kb = 0; kb < 32; ++kb){
    const int k0 = kb*32 + g*8;
    bf16x8 a[2], b[2];
    #pragma unroll
    for (int rt=0;rt<2;++rt)
      a[rt] = *(const bf16x8*)(ctx + ((size_t)(tb0 + wm*32 + rt*16 + li)*16 + h)*1024 + k0);
    #pragma unroll
    for (int ct=0;ct<2;++ct)
      b[ct] = *(const bf16x8*)(WvT + (size_t)(h*64 + wn*32 + ct*16 + li)*1024 + k0);
    #pragma unroll
    for (int rt=0;rt<2;++rt)
      #pragma unroll
      for (int ct=0;ct<2;++ct)
        acc[rt][ct] = MFMA16(a[rt], b[ct], acc[rt][ct]);
  }
  #pragma unroll
  for (int rt=0;rt<2;++rt)
    #pragma unroll
    for (int ct=0;ct<2;++ct)
      #pragma unroll
      for (int r=0;r<4;++r){
        int m = tb0 + wm*32 + rt*16 + g*4 + r;
        int dout = h*64 + wn*32 + ct*16 + li;
        out_att[(size_t)m*1024 + dout] = acc[rt][ct][r] + bv[dout];
      }
}

// ---------------- launch ----------------
extern "C" void kernel_launch(void* const* d_in, const int* in_sizes, int n_in,
                              void* d_out, int out_size, void* d_ws, size_t ws_size,
                              hipStream_t stream){
  const float* qv     = (const float*)d_in[0];
  const float* tokens = (const float*)d_in[1];
  const float* gate   = (const float*)d_in[2];
  const float* Wq     = (const float*)d_in[3];
  const float* bq     = (const float*)d_in[4];
  const float* Wk     = (const float*)d_in[5];
  const float* bk     = (const float*)d_in[6];
  const float* Wv     = (const float*)d_in[7];
  const float* bv     = (const float*)d_in[8];

  char* ws = (char*)d_ws;
  u16*   WqT = (u16*)(ws);                       // 2 MB
  u16*   WkB = (u16*)(ws + (2u<<20));            // 2 MB
  u16*   WvT = (u16*)(ws + (4u<<20));            // 2 MB
  float* qf  = (float*)(ws + (6u<<20));          // 4 MB
  u16*   qb  = (u16*)(ws + (10u<<20));           // 2 MB
  u16*   U   = (u16*)(ws + (12u<<20));           // 32 MB
  u16*   ctxb= (u16*)(ws + (44u<<20));           // 32 MB  (total 76 MB)

  float* out_att    = (float*)d_out;
  float* out_mean   = out_att + 1048576;
  float* out_logits = out_att + 1114112;

  (void)hipFuncSetAttribute((const void*)k_attn,
                            hipFuncAttributeMaxDynamicSharedMemorySize, K3_LDS);
  k_convert <<<dim3(256, 3),    256, 0,      stream>>>(Wq, Wk, Wv, WqT, WkB, WvT);
  k_qproj   <<<dim3(16, 16),    256, 0,      stream>>>(qv, WqT, bq, qf, qb);
  k_umat    <<<dim3(16, 16, 16),256, 0,      stream>>>(qb, WkB, U);
  k_attn    <<<dim3(1024),      256, K3_LDS, stream>>>(tokens, gate, U, qf, bk,
                                                       out_logits, out_mean, ctxb);
  k_attended<<<dim3(16, 16),    256, 0,      stream>>>(ctxb, WvT, bv, out_att);
}

// Round 6
// 159.638 us; speedup vs baseline: 1.5631x; 1.5631x over previous
//
#include <hip/hip_runtime.h>
#include <hip/hip_bf16.h>

typedef __attribute__((ext_vector_type(4))) float f32x4;
typedef __attribute__((ext_vector_type(8))) short bf16x8;
typedef unsigned int u32;
typedef unsigned short u16;

#define DEV static __device__ __forceinline__

// T=32,B=32 -> TB=1024 ; N=64 ; D=1024 ; H=16 ; HD=64
// d_out: attended [1024x1024] f32 @0 ; mean_attn [1024x64] @1048576 ; logits [1024x16x64] @1114112

DEV u16 f2bf(float x){                       // RNE f32->bf16
  union { float f; u32 u; } v; v.f = x;
  u32 r = v.u + 0x7FFFu + ((v.u >> 16) & 1u);
  return (u16)(r >> 16);
}
DEV float bf2f(u16 s){
  union { u32 u; float f; } v; v.u = ((u32)s) << 16;
  return v.f;
}

#define MFMA16(a,b,c) __builtin_amdgcn_mfma_f32_16x16x32_bf16((a),(b),(c),0,0,0)

// f32 token-buffer swizzle (8-token rounds): XOR byte bits 4-6 by a token hash.
// Involution; 16B-granular so global_load_lds source stays 16B-aligned & coalesced.
#define SWZ(n) ((((n)&3)<<5) | ((((n)>>2)&1)<<4))

// lgkm-only block barrier: orders LDS, does NOT drain vmcnt (keeps global_load_lds
// staging in flight across it).
DEV void bar_lgkm(){
  __builtin_amdgcn_sched_barrier(0);
  asm volatile("s_waitcnt lgkmcnt(0)" ::: "memory");
  __builtin_amdgcn_s_barrier();
  __builtin_amdgcn_sched_barrier(0);
}
// full barrier: drains staging (vmcnt) + LDS, then barrier.
DEV void bar_full(){
  __builtin_amdgcn_sched_barrier(0);
  asm volatile("s_waitcnt vmcnt(0) lgkmcnt(0)" ::: "memory");
  __builtin_amdgcn_s_barrier();
  __builtin_amdgcn_sched_barrier(0);
}

// 8x f32 -> bf16x8 via packed RNE converts
DEV bf16x8 cvt8(f32x4 lo, f32x4 hi){
  union { u32 u[4]; bf16x8 v; } r;
  asm("v_cvt_pk_bf16_f32 %0, %1, %2" : "=v"(r.u[0]) : "v"(lo.x), "v"(lo.y));
  asm("v_cvt_pk_bf16_f32 %0, %1, %2" : "=v"(r.u[1]) : "v"(lo.z), "v"(lo.w));
  asm("v_cvt_pk_bf16_f32 %0, %1, %2" : "=v"(r.u[2]) : "v"(hi.x), "v"(hi.y));
  asm("v_cvt_pk_bf16_f32 %0, %1, %2" : "=v"(r.u[3]) : "v"(hi.z), "v"(hi.w));
  return r.v;
}

// Stage 8 tokens (f32, 32KB) of (tbn, tk0..tk0+7) into buffer bb via async
// global_load_lds; wave w stages tokens {2w, 2w+1}. LDS dest is linear (HW:
// wave-uniform base + lane*16); the bank swizzle is applied by pre-swizzling the
// per-lane GLOBAL source address: LDS[y] = G[y ^ SWZ(tok)], reader uses
// LDS[x ^ SWZ(tok)] = G[x].
DEV void stage8(const float* __restrict__ tokens, int tbn, int tk0,
                char* smem, int bb, int w, int l){
  char* ldsb = smem + (size_t)bb*32768 + (size_t)w*8192;
  const char* gb = (const char*)tokens + (size_t)tbn*262144 + (size_t)tk0*4096;
  #pragma unroll
  for (int j = 0; j < 8; ++j){
    const int nloc  = w*2 + (j >> 2);
    const int inner = (((j & 3)*1024) + l*16) ^ SWZ(nloc);
    __builtin_amdgcn_global_load_lds(
        (const __attribute__((address_space(1))) u32*)(gb + (size_t)nloc*4096 + inner),
        (__attribute__((address_space(3))) u32*)(ldsb + j*1024),
        16, 0, 0);
  }
}

// ============================ 5-kernel pipeline (the timed path) ============================
__global__ __launch_bounds__(256) void k_convert(
    const float* __restrict__ Wq, const float* __restrict__ Wk, const float* __restrict__ Wv,
    u16* __restrict__ WqT, u16* __restrict__ WkB, u16* __restrict__ WvT){
  __shared__ u16 tile[64][65];
  const int which = blockIdx.y;
  const float* src = which==0 ? Wq : (which==1 ? Wk : Wv);
  const int bi = (blockIdx.x >> 4) << 6;
  const int bj = (blockIdx.x & 15) << 6;
  const int t  = threadIdx.x;
  #pragma unroll
  for (int k2 = 0; k2 < 16; ++k2){
    int e = t + (k2 << 8);
    int r = e >> 6, c = e & 63;
    tile[r][c] = f2bf(src[(size_t)(bi + r)*1024 + bj + c]);
  }
  __syncthreads();
  if (which == 1){
    #pragma unroll
    for (int k2 = 0; k2 < 16; ++k2){
      int e = t + (k2 << 8); int r = e >> 6, c = e & 63;
      WkB[(size_t)(bi + r)*1024 + bj + c] = tile[r][c];
    }
  } else {
    u16* dst = which==0 ? WqT : WvT;
    #pragma unroll
    for (int k2 = 0; k2 < 16; ++k2){
      int e = t + (k2 << 8); int r = e >> 6, c = e & 63;
      dst[(size_t)(bj + r)*1024 + bi + c] = tile[c][r];
    }
  }
}

__global__ __launch_bounds__(256) void k_qproj(
    const float* __restrict__ qv, const u16* __restrict__ WqT, const float* __restrict__ bq,
    float* __restrict__ qf, u16* __restrict__ qb){
  const int l = threadIdx.x & 63, w = threadIdx.x >> 6;
  const int wm = w & 1, wn = w >> 1;
  const int g = l >> 4, li = l & 15;
  const int m_base = blockIdx.x*64 + wm*32;
  const int n_base = blockIdx.y*64 + wn*32;
  f32x4 acc[2][2];
  #pragma unroll
  for (int i=0;i<2;++i)
    #pragma unroll
    for (int j=0;j<2;++j) acc[i][j] = (f32x4)0.0f;

  #pragma unroll 4
  for (int kb = 0; kb < 32; ++kb){
    const int k0 = kb*32 + g*8;
    bf16x8 a[2], b[2];
    #pragma unroll
    for (int rt = 0; rt < 2; ++rt){
      const float* p = qv + (size_t)(m_base + rt*16 + li)*1024 + k0;
      f32x4 lo = *(const f32x4*)p;
      f32x4 hi = *(const f32x4*)(p+4);
      union { u16 s[8]; bf16x8 v; } u;
      u.s[0]=f2bf(lo.x); u.s[1]=f2bf(lo.y); u.s[2]=f2bf(lo.z); u.s[3]=f2bf(lo.w);
      u.s[4]=f2bf(hi.x); u.s[5]=f2bf(hi.y); u.s[6]=f2bf(hi.z); u.s[7]=f2bf(hi.w);
      a[rt] = u.v;
    }
    #pragma unroll
    for (int ct = 0; ct < 2; ++ct)
      b[ct] = *(const bf16x8*)(WqT + (size_t)(n_base + ct*16 + li)*1024 + k0);
    #pragma unroll
    for (int rt = 0; rt < 2; ++rt)
      #pragma unroll
      for (int ct = 0; ct < 2; ++ct)
        acc[rt][ct] = MFMA16(a[rt], b[ct], acc[rt][ct]);
  }
  #pragma unroll
  for (int rt=0;rt<2;++rt)
    #pragma unroll
    for (int ct=0;ct<2;++ct)
      #pragma unroll
      for (int r=0;r<4;++r){
        int m = m_base + rt*16 + g*4 + r;   // C/D map: row=(lane>>4)*4+reg, col=lane&15
        int n = n_base + ct*16 + li;
        float val = acc[rt][ct][r] + bq[n];
        qf[(size_t)m*1024 + n] = val;
        qb[(size_t)m*1024 + n] = f2bf(val);
      }
}

__global__ __launch_bounds__(256) void k_umat(
    const u16* __restrict__ qb, const u16* __restrict__ WkB, u16* __restrict__ U){
  __shared__ __align__(16) u16 stile[64][64];
  const int l = threadIdx.x & 63, w = threadIdx.x >> 6;
  const int wm = w & 1, wn = w >> 1, g = l >> 4, li = l & 15;
  const int tb0 = blockIdx.x*64, d0 = blockIdx.y*64, h = blockIdx.z;
  f32x4 acc[2][2];
  #pragma unroll
  for (int i=0;i<2;++i)
    #pragma unroll
    for (int j=0;j<2;++j) acc[i][j] = (f32x4)0.0f;

  #pragma unroll
  for (int kb = 0; kb < 2; ++kb){
    const int k0 = h*64 + kb*32 + g*8;
    bf16x8 a[2], b[2];
    #pragma unroll
    for (int rt=0;rt<2;++rt)
      a[rt] = *(const bf16x8*)(qb + (size_t)(tb0 + wm*32 + rt*16 + li)*1024 + k0);
    #pragma unroll
    for (int ct=0;ct<2;++ct)
      b[ct] = *(const bf16x8*)(WkB + (size_t)(d0 + wn*32 + ct*16 + li)*1024 + k0);
    #pragma unroll
    for (int rt=0;rt<2;++rt)
      #pragma unroll
      for (int ct=0;ct<2;++ct)
        acc[rt][ct] = MFMA16(a[rt], b[ct], acc[rt][ct]);
  }
  #pragma unroll
  for (int rt=0;rt<2;++rt)
    #pragma unroll
    for (int ct=0;ct<2;++ct)
      #pragma unroll
      for (int r=0;r<4;++r)
        stile[wm*32 + rt*16 + g*4 + r][wn*32 + ct*16 + li] = f2bf(acc[rt][ct][r]);
  __syncthreads();
  const int r = threadIdx.x >> 2, cg4 = threadIdx.x & 3;
  f32x4* dst = (f32x4*)(U + ((size_t)(tb0 + r)*16 + h)*1024 + d0 + cg4*16);
  const f32x4* s4 = (const f32x4*)(&stile[r][cg4*16]);
  dst[0] = s4[0]; dst[1] = s4[1];
}

// ---- k_attn: async double-buffered token stream, 2-barrier rounds ----
// 8 rounds x 8 tokens (f32 in LDS), 2x32KB buffers -> 2 blocks/CU (R4 geometry, the
// best measured). Per-round fixed-cost cuts vs R4/R5 (which measured ~6.2us/round,
// payload-independent):
//   * 3 barriers -> 2: after the QK^T-partial barrier each wave computes softmax for
//     ITS OWN 4 PV heads (gathers the 4 wave-partials itself); p_s is then produced
//     and consumed by the SAME wave -> no pre-PV barrier (same-wave lgkm ordering).
//   * no global ops in the loop except staging: out_logits deferred to epilogue,
//     gate preloaded to LDS -> the round-top vmcnt(0) drains staging loads only
//     (global stores also count in vmcnt!).
//   * rsc via __shfl broadcast instead of an LDS round-trip.
#define K3_LDS 65536
__global__ __launch_bounds__(256, 2) void k_attn(
    const float* __restrict__ tokens, const float* __restrict__ gate,
    const u16* __restrict__ U, const float* __restrict__ qf, const float* __restrict__ bk,
    float* __restrict__ out_logits, float* __restrict__ out_mean, u16* __restrict__ ctx){
  extern __shared__ __align__(16) char smem[];
  __shared__ __align__(16) char sstat[9152];
  float* part_s   = (float*)(sstat);          // [4][64][4] 4096B
  float* logits_s = (float*)(sstat + 4096);   // [16][64]   4096B
  float* p_s      = (float*)(sstat + 8192);   // [8][16]    512B
  float* csum     = (float*)(sstat + 8704);   // [16]       64B
  float* gate_s   = (float*)(sstat + 8768);   // [64]       256B
  float* mzs      = (float*)(sstat + 9024);   // [16][2]    128B
  const int tb = blockIdx.x;
  const int tid = threadIdx.x;
  const int l = tid & 63, w = tid >> 6, g = l >> 4, li = l & 15;
  const int sh = tid >> 4, sj = tid & 15;

  // per-tb A-fragments: U[tb][h=li][D-slice of wave w]
  bf16x8 a[8];
  const bf16x8* Ub = (const bf16x8*)(U + (size_t)tb*16384);
  #pragma unroll
  for (int i = 0; i < 8; ++i)
    a[i] = Ub[li*128 + (w*8 + i)*4 + g];

  // gate -> LDS (once); csum[h] = q[tb, h*64:] . bk[h*64:]
  if (tid < 64) gate_s[tid] = gate[(size_t)tb*64 + tid];
  {
    const float* qp = qf + (size_t)tb*1024 + sh*64 + sj*4;
    const float* bp = bk + sh*64 + sj*4;
    float part = qp[0]*bp[0] + qp[1]*bp[1] + qp[2]*bp[2] + qp[3]*bp[3];
    part += __shfl_xor(part, 1); part += __shfl_xor(part, 2);
    part += __shfl_xor(part, 4); part += __shfl_xor(part, 8);
    if (sj == 0) csum[sh] = part;
  }

  // this lane's softmax slot: head hme (one of this wave's 4 PV heads), token nme
  const int hl  = (l >> 3) & 3;
  const int hme = w*4 + hl;
  const int nme = l & 7;

  float m_run = -1e30f, z_run = 0.0f;
  f32x4 cacc[4][4];
  #pragma unroll
  for (int i=0;i<4;++i)
    #pragma unroll
    for (int j=0;j<4;++j) cacc[i][j] = (f32x4)0.0f;

  stage8(tokens, tb, 0, smem, 0, w, l);       // prologue: chunk 0 -> buf0

  for (int r = 0; r < 8; ++r){
    const int n0 = r*8;
    char* bufc = smem + (size_t)(r & 1)*32768;

    bar_full();                               // (A) stage for r landed; buf[(r+1)&1] free
    if (r + 1 < 8)
      stage8(tokens, tb, (r+1)*8, smem, (r+1) & 1, w, l);

    // ---- QK^T: 8 tokens, K split 4 ways across waves; f32->bf16 at read ----
    {
      const int row = li & 7;                 // cols 8..15 duplicate rows (discarded)
      const int sw  = SWZ(row);
      f32x4 acc = (f32x4)0.0f;
      #pragma unroll
      for (int i = 0; i < 8; ++i){
        const int p0b = (w*8 + i)*128 + g*32;
        f32x4 lo = *(const f32x4*)(bufc + row*4096 + ((p0b     ) ^ sw));
        f32x4 hi = *(const f32x4*)(bufc + row*4096 + ((p0b + 16) ^ sw));
        acc = MFMA16(a[i], cvt8(lo, hi), acc);
      }
      *(f32x4*)(part_s + (size_t)(w*64 + l)*4) = acc;
    }
    bar_lgkm();                               // (B) part_s visible

    // ---- per-wave softmax for THIS wave's 4 PV heads (lanes 32-63 duplicate) ----
    float rsc;
    {
      // partial for (hme, nme) sits in wave wv's part_s at
      //   (wv*64 + (hme>>2)*16 + nme)*4 + (hme&3); hme>>2 == w.
      const int base = w*64 + nme*4 + (hme & 3);   // dword index pattern, conflict-free
      float lv = part_s[base] + part_s[256 + base] + part_s[512 + base] + part_s[768 + base];
      lv = (lv + csum[hme])*0.125f + gate_s[n0 + nme];
      float cm = lv;
      cm = fmaxf(cm, __shfl_xor(cm, 1));
      cm = fmaxf(cm, __shfl_xor(cm, 2));
      cm = fmaxf(cm, __shfl_xor(cm, 4));      // max over the 8-token octet
      float m_new = fmaxf(m_run, cm);
      rsc = __expf(m_run - m_new);
      float p0 = __expf(lv - m_new);
      float zs = p0;
      zs += __shfl_xor(zs, 1); zs += __shfl_xor(zs, 2); zs += __shfl_xor(zs, 4);
      z_run = z_run * rsc + zs;
      m_run = m_new;
      if (l < 32){
        p_s[nme*16 + hme] = p0;               // consumed by THIS wave's PV only
        logits_s[hme*64 + n0 + nme] = lv;
      }
    }
    // no barrier: p_s/logits_s written and read by the same wave (lgkm auto-ordered)

    // ---- PV: f32 tokens direct from LDS, contiguous reads ----
    {
      float rr4[4];
      #pragma unroll
      for (int hh = 0; hh < 4; ++hh) rr4[hh] = __shfl(rsc, hh*8);
      #pragma unroll
      for (int dq = 0; dq < 4; ++dq)
        #pragma unroll
        for (int hh = 0; hh < 4; ++hh) cacc[dq][hh] *= rr4[hh];
      #pragma unroll
      for (int nl = 0; nl < 8; ++nl){
        const f32x4 p = *(const f32x4*)(p_s + nl*16 + w*4);
        const int swn = SWZ(nl);
        #pragma unroll
        for (int dq = 0; dq < 4; ++dq){
          const f32x4 t = *(const f32x4*)(bufc + (size_t)nl*4096 + ((dq*1024 + l*16) ^ swn));
          #pragma unroll
          for (int hh = 0; hh < 4; ++hh)
            cacc[dq][hh] += t * p[hh];
        }
      }
    }
  }

  // ---- finalize per-head m,z (one lane per head) ----
  if (l < 32 && (l & 7) == 0){
    mzs[hme*2]     = m_run;
    mzs[hme*2 + 1] = 1.0f / z_run;
  }
  bar_lgkm();                                 // logits_s + mzs visible to all

  // ---- epilogue: out_logits (deferred), mean_attn, ctx ----
  {
    f32x4 v = *(const f32x4*)(logits_s + tid*4);
    *(f32x4*)(out_logits + (size_t)tb*1024 + tid*4) = v;
  }
  if (tid < 64){
    float s = 0.0f;
    #pragma unroll
    for (int h = 0; h < 16; ++h)
      s += __expf(logits_s[h*64 + tid] - mzs[h*2]) * mzs[h*2 + 1];
    out_mean[(size_t)tb*64 + tid] = s * 0.0625f;
  }
  #pragma unroll
  for (int hh = 0; hh < 4; ++hh){
    const int h = w*4 + hh;
    const float zinv = mzs[h*2 + 1];
    #pragma unroll
    for (int dq = 0; dq < 4; ++dq){
      f32x4 v = cacc[dq][hh];
      uint2 pk;
      pk.x = (u32)f2bf(v.x * zinv) | ((u32)f2bf(v.y * zinv) << 16);
      pk.y = (u32)f2bf(v.z * zinv) | ((u32)f2bf(v.w * zinv) << 16);
      *(uint2*)(ctx + ((size_t)tb*16 + h)*1024 + dq*256 + l*4) = pk;
    }
  }
}

__global__ __launch_bounds__(256) void k_attended(
    const u16* __restrict__ ctx, const u16* __restrict__ WvT, const float* __restrict__ bv,
    float* __restrict__ out_att){
  const int l = threadIdx.x & 63, w = threadIdx.x >> 6;
  const int wm = w & 1, wn = w >> 1, g = l >> 4, li = l & 15;
  const int tb0 = blockIdx.x*64, h = blockIdx.y;
  f32x4 acc[2][2];
  #pragma unroll
  for (int i=0;i<2;++i)
    #pragma unroll
    for (int j=0;j<2;++j) acc[i][j] = (f32x4)0.0f;

  #pragma unroll 4
  for (int kb = 0; kb < 32; ++kb){
    const int k0 = kb*32 + g*8;
    bf16x8 a[2], b[2];
    #pragma unroll
    for (int rt=0;rt<2;++rt)
      a[rt] = *(const bf16x8*)(ctx + ((size_t)(tb0 + wm*32 + rt*16 + li)*16 + h)*1024 + k0);
    #pragma unroll
    for (int ct=0;ct<2;++ct)
      b[ct] = *(const bf16x8*)(WvT + (size_t)(h*64 + wn*32 + ct*16 + li)*1024 + k0);
    #pragma unroll
    for (int rt=0;rt<2;++rt)
      #pragma unroll
      for (int ct=0;ct<2;++ct)
        acc[rt][ct] = MFMA16(a[rt], b[ct], acc[rt][ct]);
  }
  #pragma unroll
  for (int rt=0;rt<2;++rt)
    #pragma unroll
    for (int ct=0;ct<2;++ct)
      #pragma unroll
      for (int r=0;r<4;++r){
        int m = tb0 + wm*32 + rt*16 + g*4 + r;
        int dout = h*64 + wn*32 + ct*16 + li;
        out_att[(size_t)m*1024 + dout] = acc[rt][ct][r] + bv[dout];
      }
}

// ---------------- launch ----------------
extern "C" void kernel_launch(void* const* d_in, const int* in_sizes, int n_in,
                              void* d_out, int out_size, void* d_ws, size_t ws_size,
                              hipStream_t stream){
  const float* qv     = (const float*)d_in[0];
  const float* tokens = (const float*)d_in[1];
  const float* gate   = (const float*)d_in[2];
  const float* Wq     = (const float*)d_in[3];
  const float* bq     = (const float*)d_in[4];
  const float* Wk     = (const float*)d_in[5];
  const float* bk     = (const float*)d_in[6];
  const float* Wv     = (const float*)d_in[7];
  const float* bv     = (const float*)d_in[8];

  char* ws = (char*)d_ws;
  u16*   WqT = (u16*)(ws);                       // 2 MB
  u16*   WkB = (u16*)(ws + (2u<<20));            // 2 MB
  u16*   WvT = (u16*)(ws + (4u<<20));            // 2 MB
  float* qf  = (float*)(ws + (6u<<20));          // 4 MB
  u16*   qb  = (u16*)(ws + (10u<<20));           // 2 MB
  u16*   U   = (u16*)(ws + (12u<<20));           // 32 MB
  u16*   ctxb= (u16*)(ws + (44u<<20));           // 32 MB  (total 76 MB)

  float* out_att    = (float*)d_out;
  float* out_mean   = out_att + 1048576;
  float* out_logits = out_att + 1114112;

  (void)hipFuncSetAttribute((const void*)k_attn,
                            hipFuncAttributeMaxDynamicSharedMemorySize, K3_LDS);
  k_convert <<<dim3(256, 3),    256, 0,      stream>>>(Wq, Wk, Wv, WqT, WkB, WvT);
  k_qproj   <<<dim3(16, 16),    256, 0,      stream>>>(qv, WqT, bq, qf, qb);
  k_umat    <<<dim3(16, 16, 16),256, 0,      stream>>>(qb, WkB, U);
  k_attn    <<<dim3(1024),      256, K3_LDS, stream>>>(tokens, gate, U, qf, bk,
                                                       out_logits, out_mean, ctxb);
  k_attended<<<dim3(16, 16),    256, 0,      stream>>>(ctxb, WvT, bv, out_att);
}